// Round 1
// baseline (39.416 us; speedup 1.0000x reference)
//
#include <hip/hip_runtime.h>

// Problem constants
#define BB 32   // batch
#define NN 512  // ragged items (reduced axis)
#define SS 32   // static input size (rows per token tile)
#define WW 64   // attention layer width (K of GEMM1, also hidden width)
#define PP 64   // layer param (output features)

#define NCHUNK 16              // n's per block
#define CHB    (NN / NCHUNK)   // 32 chunks per b

typedef __attribute__((ext_vector_type(8))) short bf16x8;  // 8 bf16 (4 VGPRs)
typedef __attribute__((ext_vector_type(4))) float f32x4;   // MFMA accumulator

// round-to-nearest-even f32 -> bf16 bits
__device__ __forceinline__ short f2bf(float v) {
    unsigned u = __builtin_bit_cast(unsigned, v);
    u = (u + 0x7FFFu + ((u >> 16) & 1u)) >> 16;
    return (short)u;
}

// Kernel 1: Hacc[b][s][w] = sum_n relu(x[b,n,s,:] @ W1[:,w] + b1[w])
// grid = BB*CHB blocks, 256 threads (4 waves). Each wave: 4 tokens.
__global__ __launch_bounds__(256) void pool1(const float* __restrict__ x,
                                             const float* __restrict__ W1,
                                             const float* __restrict__ b1,
                                             float* __restrict__ Hacc) {
    const int tid   = threadIdx.x;
    const int wv    = tid >> 6;       // wave 0..3
    const int lane  = tid & 63;
    const int g     = lane >> 4;      // lane group 0..3
    const int q     = lane & 15;
    const int b     = blockIdx.x >> 5;     // CHB == 32
    const int chunk = blockIdx.x & 31;

    // W1 fragments (B operand): wfrag[nt][ks] elem j = W1[ks*32+g*8+j][nt*16+q]
    bf16x8 wfrag[4][2];
#pragma unroll
    for (int nt = 0; nt < 4; ++nt) {
#pragma unroll
        for (int ks = 0; ks < 2; ++ks) {
            bf16x8 f;
#pragma unroll
            for (int j = 0; j < 8; ++j)
                f[j] = f2bf(W1[(ks * 32 + g * 8 + j) * WW + nt * 16 + q]);
            wfrag[nt][ks] = f;
        }
    }

    float bias[4];
#pragma unroll
    for (int nt = 0; nt < 4; ++nt) bias[nt] = b1[nt * 16 + q];

    f32x4 hrun[2][4];
#pragma unroll
    for (int mt = 0; mt < 2; ++mt)
#pragma unroll
        for (int nt = 0; nt < 4; ++nt)
            hrun[mt][nt] = (f32x4){0.f, 0.f, 0.f, 0.f};

    const int n0 = chunk * NCHUNK + wv * 4;
#pragma unroll
    for (int t = 0; t < 4; ++t) {
        const float* rowbase = x + ((size_t)(b * NN + n0 + t)) * (SS * WW);
        // A fragments: afrag[mt][ks] elem j = x[row = mt*16+q][col = ks*32+g*8+j]
        bf16x8 afrag[2][2];
#pragma unroll
        for (int mt = 0; mt < 2; ++mt) {
#pragma unroll
            for (int ks = 0; ks < 2; ++ks) {
                const float4* p = reinterpret_cast<const float4*>(
                    rowbase + (mt * 16 + q) * WW + ks * 32 + g * 8);
                float4 v0 = p[0];
                float4 v1 = p[1];
                bf16x8 f;
                f[0] = f2bf(v0.x); f[1] = f2bf(v0.y); f[2] = f2bf(v0.z); f[3] = f2bf(v0.w);
                f[4] = f2bf(v1.x); f[5] = f2bf(v1.y); f[6] = f2bf(v1.z); f[7] = f2bf(v1.w);
                afrag[mt][ks] = f;
            }
        }
#pragma unroll
        for (int mt = 0; mt < 2; ++mt) {
#pragma unroll
            for (int nt = 0; nt < 4; ++nt) {
                f32x4 acc = (f32x4){0.f, 0.f, 0.f, 0.f};
                acc = __builtin_amdgcn_mfma_f32_16x16x32_bf16(afrag[mt][0], wfrag[nt][0], acc, 0, 0, 0);
                acc = __builtin_amdgcn_mfma_f32_16x16x32_bf16(afrag[mt][1], wfrag[nt][1], acc, 0, 0, 0);
                // bias + relu per token, accumulate over n in fp32
#pragma unroll
                for (int r = 0; r < 4; ++r)
                    hrun[mt][nt][r] += fmaxf(acc[r] + bias[nt], 0.f);
            }
        }
    }

    // cross-wave reduce in LDS, then one atomicAdd per element per block
    __shared__ float lds[4][SS * WW];
#pragma unroll
    for (int mt = 0; mt < 2; ++mt)
#pragma unroll
        for (int nt = 0; nt < 4; ++nt)
#pragma unroll
            for (int r = 0; r < 4; ++r)
                lds[wv][(mt * 16 + g * 4 + r) * WW + nt * 16 + q] = hrun[mt][nt][r];
    __syncthreads();

    for (int idx = tid; idx < SS * WW; idx += 256) {
        float s = lds[0][idx] + lds[1][idx] + lds[2][idx] + lds[3][idx];
        atomicAdd(&Hacc[b * (SS * WW) + idx], s);
    }
}

// Kernel 2: out[b,s,p] = sum_w Hacc[b,s,w] * W2[w,p] + NN * b2[p]
// 1024 rows; 256 blocks x 256 threads (4 rows per block, 1 wave per row)
__global__ __launch_bounds__(256) void pool2(const float* __restrict__ Hacc,
                                             const float* __restrict__ W2,
                                             const float* __restrict__ b2,
                                             float* __restrict__ out) {
    const int p   = threadIdx.x & 63;
    const int row = blockIdx.x * 4 + (threadIdx.x >> 6);
    const float* h = Hacc + row * WW;
    float acc = (float)NN * b2[p];
#pragma unroll
    for (int w = 0; w < WW; ++w)
        acc = fmaf(h[w], W2[w * PP + p], acc);
    out[row * PP + p] = acc;
}

extern "C" void kernel_launch(void* const* d_in, const int* in_sizes, int n_in,
                              void* d_out, int out_size, void* d_ws, size_t ws_size,
                              hipStream_t stream) {
    const float* x  = (const float*)d_in[0];
    const float* W1 = (const float*)d_in[1];
    const float* b1 = (const float*)d_in[2];
    const float* W2 = (const float*)d_in[3];
    const float* b2 = (const float*)d_in[4];
    float* out  = (float*)d_out;
    float* Hacc = (float*)d_ws;  // BB*SS*WW floats = 256 KiB

    hipMemsetAsync(Hacc, 0, (size_t)BB * SS * WW * sizeof(float), stream);
    pool1<<<dim3(BB * CHB), dim3(256), 0, stream>>>(x, W1, b1, Hacc);
    pool2<<<dim3(BB * SS / 4), dim3(256), 0, stream>>>(Hacc, W2, b2, out);
}

// Round 2
// 34.751 us; speedup vs baseline: 1.1342x; 1.1342x over previous
//
#include <hip/hip_runtime.h>

// Problem constants
#define BB 32   // batch
#define NN 512  // ragged items (reduced axis)
#define SS 32   // static input size (rows per token tile)
#define WW 64   // attention layer width (K of GEMM1, also hidden width)
#define PP 64   // layer param (output features)

#define NCHUNK 16              // n's per block
#define CHB    (NN / NCHUNK)   // 32 chunks per b

typedef __attribute__((ext_vector_type(8))) short bf16x8;  // 8 bf16 (4 VGPRs)
typedef __attribute__((ext_vector_type(4))) float f32x4;   // MFMA accumulator

// round-to-nearest-even f32 -> bf16 bits
__device__ __forceinline__ short f2bf(float v) {
    unsigned u = __builtin_bit_cast(unsigned, v);
    u = (u + 0x7FFFu + ((u >> 16) & 1u)) >> 16;
    return (short)u;
}

// Kernel 1: part[bid][s][w] = sum_{n in chunk} relu(x[b,n,s,:] @ W1[:,w] + b1[w])
// grid = BB*CHB = 1024 blocks, 256 threads (4 waves). Each wave: 4 tokens.
// No atomics: each block writes its private 32x64 fp32 partial tile to ws.
__global__ __launch_bounds__(256) void pool1(const float* __restrict__ x,
                                             const float* __restrict__ W1,
                                             const float* __restrict__ b1,
                                             float* __restrict__ part) {
    const int tid   = threadIdx.x;
    const int wv    = tid >> 6;       // wave 0..3
    const int lane  = tid & 63;
    const int g     = lane >> 4;      // lane group 0..3
    const int q     = lane & 15;
    const int b     = blockIdx.x >> 5;     // CHB == 32
    const int chunk = blockIdx.x & 31;

    // W1 fragments (B operand): wfrag[nt][ks] elem j = W1[ks*32+g*8+j][nt*16+q]
    bf16x8 wfrag[4][2];
#pragma unroll
    for (int nt = 0; nt < 4; ++nt) {
#pragma unroll
        for (int ks = 0; ks < 2; ++ks) {
            bf16x8 f;
#pragma unroll
            for (int j = 0; j < 8; ++j)
                f[j] = f2bf(W1[(ks * 32 + g * 8 + j) * WW + nt * 16 + q]);
            wfrag[nt][ks] = f;
        }
    }

    float bias[4];
#pragma unroll
    for (int nt = 0; nt < 4; ++nt) bias[nt] = b1[nt * 16 + q];

    f32x4 hrun[2][4];
#pragma unroll
    for (int mt = 0; mt < 2; ++mt)
#pragma unroll
        for (int nt = 0; nt < 4; ++nt)
            hrun[mt][nt] = (f32x4){0.f, 0.f, 0.f, 0.f};

    const int n0 = chunk * NCHUNK + wv * 4;
#pragma unroll
    for (int t = 0; t < 4; ++t) {
        const float* rowbase = x + ((size_t)(b * NN + n0 + t)) * (SS * WW);
        // A fragments: afrag[mt][ks] elem j = x[row = mt*16+q][col = ks*32+g*8+j]
        bf16x8 afrag[2][2];
#pragma unroll
        for (int mt = 0; mt < 2; ++mt) {
#pragma unroll
            for (int ks = 0; ks < 2; ++ks) {
                const float4* p = reinterpret_cast<const float4*>(
                    rowbase + (mt * 16 + q) * WW + ks * 32 + g * 8);
                float4 v0 = p[0];
                float4 v1 = p[1];
                bf16x8 f;
                f[0] = f2bf(v0.x); f[1] = f2bf(v0.y); f[2] = f2bf(v0.z); f[3] = f2bf(v0.w);
                f[4] = f2bf(v1.x); f[5] = f2bf(v1.y); f[6] = f2bf(v1.z); f[7] = f2bf(v1.w);
                afrag[mt][ks] = f;
            }
        }
#pragma unroll
        for (int mt = 0; mt < 2; ++mt) {
#pragma unroll
            for (int nt = 0; nt < 4; ++nt) {
                f32x4 acc = (f32x4){0.f, 0.f, 0.f, 0.f};
                acc = __builtin_amdgcn_mfma_f32_16x16x32_bf16(afrag[mt][0], wfrag[nt][0], acc, 0, 0, 0);
                acc = __builtin_amdgcn_mfma_f32_16x16x32_bf16(afrag[mt][1], wfrag[nt][1], acc, 0, 0, 0);
                // bias + relu per token, accumulate over n in fp32
#pragma unroll
                for (int r = 0; r < 4; ++r)
                    hrun[mt][nt][r] += fmaxf(acc[r] + bias[nt], 0.f);
            }
        }
    }

    // cross-wave reduce in LDS, then vectorized plain stores (no atomics)
    __shared__ float lds[4][SS * WW];
#pragma unroll
    for (int mt = 0; mt < 2; ++mt)
#pragma unroll
        for (int nt = 0; nt < 4; ++nt)
#pragma unroll
            for (int r = 0; r < 4; ++r)
                lds[wv][(mt * 16 + g * 4 + r) * WW + nt * 16 + q] = hrun[mt][nt][r];
    __syncthreads();

    float* dst = part + (size_t)blockIdx.x * (SS * WW);
#pragma unroll
    for (int k = 0; k < 2; ++k) {
        const int idx = tid * 4 + k * 1024;
        float4 v0 = *reinterpret_cast<const float4*>(&lds[0][idx]);
        float4 v1 = *reinterpret_cast<const float4*>(&lds[1][idx]);
        float4 v2 = *reinterpret_cast<const float4*>(&lds[2][idx]);
        float4 v3 = *reinterpret_cast<const float4*>(&lds[3][idx]);
        float4 s;
        s.x = (v0.x + v1.x) + (v2.x + v3.x);
        s.y = (v0.y + v1.y) + (v2.y + v3.y);
        s.z = (v0.z + v1.z) + (v2.z + v3.z);
        s.w = (v0.w + v1.w) + (v2.w + v3.w);
        *reinterpret_cast<float4*>(&dst[idx]) = s;
    }
}

// Kernel 2: out[b,s,p] = sum_w (sum_c part[b*32+c][s][w]) * W2[w,p] + NN * b2[p]
// 1024 output rows; 256 blocks x 256 threads, one wave per row.
__global__ __launch_bounds__(256) void pool2(const float* __restrict__ part,
                                             const float* __restrict__ W2,
                                             const float* __restrict__ b2,
                                             float* __restrict__ out) {
    const int tid  = threadIdx.x;
    const int wv   = tid >> 6;
    const int lane = tid & 63;
    const int row  = blockIdx.x * 4 + wv;   // row = b*SS + s
    const int b    = row >> 5;              // SS == 32
    const int s    = row & 31;

    // reduce the 32 chunk-partials for h[w = lane]
    float h = 0.f;
    const float* pb = part + ((size_t)b * CHB) * (SS * WW) + s * WW + lane;
#pragma unroll
    for (int c = 0; c < CHB; ++c)
        h += pb[(size_t)c * (SS * WW)];

    __shared__ float hs[4][WW];
    hs[wv][lane] = h;
    __syncthreads();

    float acc = (float)NN * b2[lane];
#pragma unroll
    for (int w = 0; w < WW; ++w)
        acc = fmaf(hs[wv][w], W2[w * PP + lane], acc);
    out[row * PP + lane] = acc;
}

extern "C" void kernel_launch(void* const* d_in, const int* in_sizes, int n_in,
                              void* d_out, int out_size, void* d_ws, size_t ws_size,
                              hipStream_t stream) {
    const float* x  = (const float*)d_in[0];
    const float* W1 = (const float*)d_in[1];
    const float* b1 = (const float*)d_in[2];
    const float* W2 = (const float*)d_in[3];
    const float* b2 = (const float*)d_in[4];
    float* out  = (float*)d_out;
    float* part = (float*)d_ws;  // BB*CHB * SS*WW floats = 8 MiB

    pool1<<<dim3(BB * CHB), dim3(256), 0, stream>>>(x, W1, b1, part);
    pool2<<<dim3(BB * SS / 4), dim3(256), 0, stream>>>(part, W2, b2, out);
}